// Round 1
// baseline (462.050 us; speedup 1.0000x reference)
//
#include <hip/hip_runtime.h>
#include <stdint.h>

// Problem constants
#define T_TOK 4096
#define D_DIM 1024
#define H_DIM 2048
#define E_EXP 8
#define K_TOP 2
#define NTK   (T_TOK * K_TOP)   // 8192 (token, slot) pairs
#define MTILE 192               // M-tile rows (3% pad waste vs 11% at 256)
#define MAX_TILES 56            // sum ceil(c_e/192) <= 8192/192 + 8 = 50.7

typedef short bf16x8 __attribute__((ext_vector_type(8)));
typedef float f32x4  __attribute__((ext_vector_type(4)));

#define MINI(a, b) ((a) < (b) ? (a) : (b))

__device__ __forceinline__ unsigned short f2bf(float f) {
  unsigned u = __float_as_uint(f);
  u += 0x7fffu + ((u >> 16) & 1u);   // round-to-nearest-even
  return (unsigned short)(u >> 16);
}

// async global->LDS, 16B per lane; lds base must be wave-uniform
#define GLDS16(gp, lp)                                                        \
  __builtin_amdgcn_global_load_lds(                                           \
      (const __attribute__((address_space(1))) void*)(gp),                    \
      (__attribute__((address_space(3))) void*)(lp), 16, 0, 0)

// meta layout (ints): [0..7] counts, [8..15] offsets, [16..23] scatter cursors,
// [24] n_tiles, [32..87] tile_expert, [112..167] tile_row0, [192..247] tile_valid

// ---- routing, parallelized (old single-block route serialized on 1 CU) ----

__global__ __launch_bounds__(256) void k_route_count(const int* __restrict__ idx,
                                                     int* __restrict__ meta) {
  __shared__ int h[E_EXP];
  int tid = threadIdx.x;
  if (tid < E_EXP) h[tid] = 0;
  __syncthreads();
  int i = blockIdx.x * 256 + tid;          // 32 blocks x 256 = 8192 exactly
  atomicAdd(&h[idx[i] & (E_EXP - 1)], 1);
  __syncthreads();
  if (tid < E_EXP) atomicAdd(&meta[tid], h[tid]);
}

__global__ __launch_bounds__(64) void k_route_plan(int* __restrict__ meta) {
  if (threadIdx.x) return;
  int off = 0, nt = 0;
  for (int e = 0; e < E_EXP; ++e) {
    int c = meta[e];
    meta[8 + e]  = off;
    meta[16 + e] = off;                     // scatter cursor
    for (int r = 0; r < c; r += MTILE) {
      meta[32 + nt]  = e;
      meta[112 + nt] = off + r;
      meta[192 + nt] = MINI(MTILE, c - r);
      ++nt;
    }
    off += c;
  }
  meta[24] = nt;
}

__global__ __launch_bounds__(256) void k_route_scatter(const int* __restrict__ idx,
                                                       const float* __restrict__ w,
                                                       int* __restrict__ meta,
                                                       int* __restrict__ rows,
                                                       float* __restrict__ wv) {
  __shared__ int h[E_EXP], base[E_EXP];
  int tid = threadIdx.x;
  if (tid < E_EXP) h[tid] = 0;
  __syncthreads();
  int i = blockIdx.x * 256 + tid;
  int e = idx[i] & (E_EXP - 1);
  int r = atomicAdd(&h[e], 1);             // block-local rank
  __syncthreads();
  if (tid < E_EXP) base[tid] = atomicAdd(&meta[16 + tid], h[tid]);
  __syncthreads();
  int p = base[e] + r;
  rows[p] = i >> 1;  // K_TOP = 2
  wv[p]   = w[i];
}

// ---- fused f32->bf16 convert, 8 floats/thread, 16B stores ----
#define NX8   (T_TOK * D_DIM / 8)               // 524288
#define NW18  (E_EXP * 2 * H_DIM * D_DIM / 8)   // 4194304
#define NW28  (E_EXP * D_DIM * H_DIM / 8)       // 2097152
#define NCVT8 (NX8 + NW18 + NW28)               // 6815744

__global__ __launch_bounds__(256) void k_cvt8(const float* __restrict__ x,
                                              const float* __restrict__ W1,
                                              const float* __restrict__ W2,
                                              unsigned short* __restrict__ xb,
                                              unsigned short* __restrict__ W1b,
                                              unsigned short* __restrict__ W2b) {
  long gid = (long)blockIdx.x * 256 + threadIdx.x;
  const float* src;
  unsigned short* dst;
  long i;
  if (gid < NX8) {
    src = x; dst = xb; i = gid;
  } else if (gid < NX8 + NW18) {
    src = W1; dst = W1b; i = gid - NX8;
  } else if (gid < NCVT8) {
    src = W2; dst = W2b; i = gid - (NX8 + NW18);
  } else return;
  float4 a = ((const float4*)src)[2 * i];
  float4 b = ((const float4*)src)[2 * i + 1];
  uint4 o;
  o.x = f2bf(a.x) | ((unsigned)f2bf(a.y) << 16);
  o.y = f2bf(a.z) | ((unsigned)f2bf(a.w) << 16);
  o.z = f2bf(b.x) | ((unsigned)f2bf(b.y) << 16);
  o.w = f2bf(b.z) | ((unsigned)f2bf(b.w) << 16);
  ((uint4*)dst)[i] = o;
}

// ---- GEMM1: h = Xg @ W1e^T (both strips), act = f2bf(u * silu(gate) * w_row)
// 512 threads (8 waves, 2M x 4N), tile M=192 x 128 act-cols (u+gate strips).
// Double-buffered LDS (112 KB, 1 block/CU), counted vmcnt(7) pipeline:
// issue next K-tile's global_load_lds, wait only for the PREVIOUS tile's 7
// loads, raw s_barrier (no vmcnt(0) drain in the main loop).
__global__ __launch_bounds__(512, 2) void k_gemm1(
    const unsigned short* __restrict__ xb,   // [T][1024] bf16
    const unsigned short* __restrict__ W1b,  // [E][4096][1024] bf16
    const int* __restrict__ meta,
    const int* __restrict__ rows,
    const float* __restrict__ wv,
    unsigned short* __restrict__ act) {      // [8192][2048] bf16
  int nt = meta[24];
  int tb = blockIdx.x;
  if (tb >= nt) return;
  int e     = meta[32 + tb];
  int r0    = meta[112 + tb];
  int valid = meta[192 + tb];
  int n0    = blockIdx.y * 128;

  __shared__ unsigned short lA[2][MTILE * 64];   // 2 x 24 KB
  __shared__ unsigned short lB1[2][128 * 64];    // 2 x 16 KB
  __shared__ unsigned short lB2[2][128 * 64];    // 2 x 16 KB

  int tid  = threadIdx.x;
  int wave = tid >> 6, lane = tid & 63;
  int wm = wave >> 2, wn = wave & 3;             // 2 x 4 wave grid

  const unsigned short* w1e = W1b + (size_t)e * (4096 * 1024);

  // staging pointers: A = 1536 16B-chunks over 512 threads (3 each), B 2 each
  const unsigned short *pA[3], *pB1[2], *pB2[2];
#pragma unroll
  for (int it = 0; it < 3; ++it) {
    int c = it * 512 + tid;
    int r = c >> 3, cc = c & 7;
    int g = cc ^ (r & 7);
    int tok = rows[r0 + MINI(r, valid - 1)];
    pA[it] = xb + (size_t)tok * 1024 + g * 8;
  }
#pragma unroll
  for (int it = 0; it < 2; ++it) {
    int c = it * 512 + tid;
    int r = c >> 3, cc = c & 7;
    int g = cc ^ (r & 7);
    pB1[it] = w1e + (size_t)(n0 + r) * 1024 + g * 8;
    pB2[it] = w1e + (size_t)(2048 + n0 + r) * 1024 + g * 8;
  }

  auto STAGE = [&](int t, int b) {
    int k0 = t * 64;
#pragma unroll
    for (int it = 0; it < 3; ++it)
      GLDS16(pA[it] + k0, &lA[b][(it * 512 + wave * 64) * 8]);
#pragma unroll
    for (int it = 0; it < 2; ++it) {
      int lb = (it * 512 + wave * 64) * 8;
      GLDS16(pB1[it] + k0, &lB1[b][lb]);
      GLDS16(pB2[it] + k0, &lB2[b][lb]);
    }
  };  // 7 GLDS per thread

  f32x4 zero = {0.f, 0.f, 0.f, 0.f};
  f32x4 au[6][2], ag[6][2];
#pragma unroll
  for (int i = 0; i < 6; ++i)
#pragma unroll
    for (int j = 0; j < 2; ++j) { au[i][j] = zero; ag[i][j] = zero; }

  int fr = lane & 15, q = lane >> 4;

  STAGE(0, 0);
  for (int t = 0; t < 16; ++t) {            // K = 1024 / BK = 64
    int cb = t & 1;
    if (t < 15) {
      STAGE(t + 1, cb ^ 1);                 // prefetch next tile
      asm volatile("s_waitcnt vmcnt(7)" ::: "memory");   // tile t done, t+1 in flight
    } else {
      asm volatile("s_waitcnt vmcnt(0)" ::: "memory");
    }
    __builtin_amdgcn_s_barrier();
    __builtin_amdgcn_sched_barrier(0);
#pragma unroll
    for (int kk = 0; kk < 2; ++kk) {
      int co = (((kk << 2) + q) ^ (fr & 7)) * 8 + fr * 64;  // swizzled read
      bf16x8 a[6];
#pragma unroll
      for (int i = 0; i < 6; ++i)
        a[i] = *(const bf16x8*)&lA[cb][(wm * 96 + i * 16) * 64 + co];
#pragma unroll
      for (int j = 0; j < 2; ++j) {
        bf16x8 bu = *(const bf16x8*)&lB1[cb][(wn * 32 + j * 16) * 64 + co];
        bf16x8 bg = *(const bf16x8*)&lB2[cb][(wn * 32 + j * 16) * 64 + co];
#pragma unroll
        for (int i = 0; i < 6; ++i) {
          au[i][j] = __builtin_amdgcn_mfma_f32_16x16x32_bf16(a[i], bu, au[i][j], 0, 0, 0);
          ag[i][j] = __builtin_amdgcn_mfma_f32_16x16x32_bf16(a[i], bg, ag[i][j], 0, 0, 0);
        }
      }
    }
    __builtin_amdgcn_s_barrier();
    __builtin_amdgcn_sched_barrier(0);
  }

#pragma unroll
  for (int i = 0; i < 6; ++i) {
#pragma unroll
    for (int reg = 0; reg < 4; ++reg) {
      int lm = wm * 96 + i * 16 + q * 4 + reg;
      if (lm < valid) {
        float wrow = wv[r0 + lm];
        size_t orow = (size_t)(r0 + lm) * 2048;
#pragma unroll
        for (int j = 0; j < 2; ++j) {
          float u = au[i][j][reg];
          float g = ag[i][j][reg];
          float s = g / (1.f + __expf(-g));
          act[orow + (n0 + wn * 32 + j * 16 + fr)] = f2bf(u * s * wrow);
        }
      }
    }
  }
}

// ---- GEMM2: out_slot = act @ W2e^T, atomicAdd into d_out (weight pre-applied).
// 256 threads (4 waves, 2x2), tile M=192 x N=128, double-buffered LDS 80 KB ->
// 2 blocks/CU, counted vmcnt(10) pipeline.
__global__ __launch_bounds__(256, 2) void k_gemm2(
    const unsigned short* __restrict__ act,  // [8192][2048] bf16
    const unsigned short* __restrict__ W2b,  // [E][1024][2048] bf16
    const int* __restrict__ meta,
    const int* __restrict__ rows,
    float* __restrict__ out) {               // [4096][1024] fp32
  int nt = meta[24];
  int tb = blockIdx.x;
  if (tb >= nt) return;
  int e     = meta[32 + tb];
  int r0    = meta[112 + tb];
  int valid = meta[192 + tb];
  int n0    = blockIdx.y * 128;

  __shared__ unsigned short lA[2][MTILE * 64];   // 2 x 24 KB
  __shared__ unsigned short lB[2][128 * 64];     // 2 x 16 KB  (total 80 KB)

  int tid  = threadIdx.x;
  int wave = tid >> 6, lane = tid & 63;
  int wm = wave >> 1, wn = wave & 1;             // 2 x 2 wave grid

  const unsigned short* w2e = W2b + (size_t)e * (1024 * 2048);

  const unsigned short *pA[6], *pB[4];
#pragma unroll
  for (int it = 0; it < 6; ++it) {
    int c = it * 256 + tid;
    int r = c >> 3, cc = c & 7;
    int g = cc ^ (r & 7);
    pA[it] = act + (size_t)(r0 + MINI(r, valid - 1)) * 2048 + g * 8;
  }
#pragma unroll
  for (int it = 0; it < 4; ++it) {
    int c = it * 256 + tid;
    int r = c >> 3, cc = c & 7;
    int g = cc ^ (r & 7);
    pB[it] = w2e + (size_t)(n0 + r) * 2048 + g * 8;
  }

  auto STAGE = [&](int t, int b) {
    int k0 = t * 64;
#pragma unroll
    for (int it = 0; it < 6; ++it)
      GLDS16(pA[it] + k0, &lA[b][(it * 256 + wave * 64) * 8]);
#pragma unroll
    for (int it = 0; it < 4; ++it)
      GLDS16(pB[it] + k0, &lB[b][(it * 256 + wave * 64) * 8]);
  };  // 10 GLDS per thread

  f32x4 zero = {0.f, 0.f, 0.f, 0.f};
  f32x4 acc[6][4];
#pragma unroll
  for (int i = 0; i < 6; ++i)
#pragma unroll
    for (int j = 0; j < 4; ++j) acc[i][j] = zero;

  int fr = lane & 15, q = lane >> 4;

  STAGE(0, 0);
  for (int t = 0; t < 32; ++t) {            // K = 2048 / BK = 64
    int cb = t & 1;
    if (t < 31) {
      STAGE(t + 1, cb ^ 1);
      asm volatile("s_waitcnt vmcnt(10)" ::: "memory");
    } else {
      asm volatile("s_waitcnt vmcnt(0)" ::: "memory");
    }
    __builtin_amdgcn_s_barrier();
    __builtin_amdgcn_sched_barrier(0);
#pragma unroll
    for (int kk = 0; kk < 2; ++kk) {
      int co = (((kk << 2) + q) ^ (fr & 7)) * 8 + fr * 64;
      bf16x8 a[6];
#pragma unroll
      for (int i = 0; i < 6; ++i)
        a[i] = *(const bf16x8*)&lA[cb][(wm * 96 + i * 16) * 64 + co];
#pragma unroll
      for (int j = 0; j < 4; ++j) {
        bf16x8 b = *(const bf16x8*)&lB[cb][(wn * 64 + j * 16) * 64 + co];
#pragma unroll
        for (int i = 0; i < 6; ++i)
          acc[i][j] = __builtin_amdgcn_mfma_f32_16x16x32_bf16(a[i], b, acc[i][j], 0, 0, 0);
      }
    }
    __builtin_amdgcn_s_barrier();
    __builtin_amdgcn_sched_barrier(0);
  }

#pragma unroll
  for (int i = 0; i < 6; ++i) {
#pragma unroll
    for (int reg = 0; reg < 4; ++reg) {
      int lm = wm * 96 + i * 16 + q * 4 + reg;
      if (lm < valid) {
        int tok = rows[r0 + lm];
        float* op = out + (size_t)tok * 1024;
#pragma unroll
        for (int j = 0; j < 4; ++j)
          atomicAdd(&op[n0 + wn * 64 + j * 16 + fr], acc[i][j][reg]);
      }
    }
  }
}

extern "C" void kernel_launch(void* const* d_in, const int* in_sizes, int n_in,
                              void* d_out, int out_size, void* d_ws, size_t ws_size,
                              hipStream_t stream) {
  const float* x  = (const float*)d_in[0];   // [T][D]
  const float* w  = (const float*)d_in[1];   // [T][K]
  const int*  idx = (const int*)d_in[2];     // [T][K]
  const float* W1 = (const float*)d_in[3];   // [E][2H][D]
  const float* W2 = (const float*)d_in[4];   // [E][D][H]
  float* out = (float*)d_out;

  char* ws = (char*)d_ws;
  unsigned short* W1b = (unsigned short*)(ws);              // 67108864 B
  unsigned short* W2b = (unsigned short*)(ws + 67108864);   // 33554432 B
  unsigned short* xb  = (unsigned short*)(ws + 100663296);  //  8388608 B
  unsigned short* act = (unsigned short*)(ws + 109051904);  // 33554432 B
  int*   rows = (int*)(ws + 142606336);                     //    32768 B
  float* wv   = (float*)(ws + 142639104);                   //    32768 B
  int*   meta = (int*)(ws + 142671872);                     //     1088 B

  hipMemsetAsync(d_out, 0, (size_t)out_size * sizeof(float), stream);
  hipMemsetAsync(meta, 0, 1088, stream);

  k_cvt8<<<(NCVT8 + 255) / 256, 256, 0, stream>>>(x, W1, W2, xb, W1b, W2b);
  k_route_count<<<32, 256, 0, stream>>>(idx, meta);
  k_route_plan<<<1, 64, 0, stream>>>(meta);
  k_route_scatter<<<32, 256, 0, stream>>>(idx, w, meta, rows, wv);

  dim3 g1(MAX_TILES, H_DIM / 128);  // (56, 16)
  dim3 g2(MAX_TILES, D_DIM / 128);  // (56, 8)
  k_gemm1<<<g1, 512, 0, stream>>>(xb, W1b, meta, rows, wv, act);
  k_gemm2<<<g2, 256, 0, stream>>>(act, W2b, meta, rows, out);
}